// Round 12
// baseline (350.421 us; speedup 1.0000x reference)
//
#include <hip/hip_runtime.h>
#include <math.h>

#define NN 20000
#define NPAD 20096          // padded rows for unguarded MFMA staging (157*128)
#define CC 256
#define HH 8
#define EE 160000
#define TE 320000
#define KVSTRIDE 512        // bytes per kv row: 32 chunks of [kr 8B | vr 8B]
#define APAN ((size_t)NPAD*32)   // u16 elems per A-operand k-panel (xbf/hbf/A2)
#define BPAN 40960               // u16 elems per Wt5 k-panel (1280*32)
#define OPAN 8192                // u16 elems per Wto k-panel (256*32)

typedef unsigned short u16;
typedef unsigned char u8;
typedef __attribute__((ext_vector_type(8))) short bf16x8;
typedef __attribute__((ext_vector_type(4))) float f32x4;
typedef __attribute__((ext_vector_type(2))) float f32x2;

__device__ __forceinline__ float gelu_exact(float x){
    return 0.5f*x*(1.0f+erff(x*0.7071067811865476f));
}
__device__ __forceinline__ u16 f2bf(float f){
    unsigned u = __float_as_uint(f);
    unsigned r = (u + 0x7fffu + ((u >> 16) & 1u)) >> 16;
    return (u16)r;
}
__device__ __forceinline__ float bf2f(unsigned s){
    return __uint_as_float(s << 16);
}
__device__ __forceinline__ uint2 enc8_fp8(const float* f){
    int t0 = __builtin_amdgcn_cvt_pk_fp8_f32(f[0], f[1], 0, false);
    t0     = __builtin_amdgcn_cvt_pk_fp8_f32(f[2], f[3], t0, true);
    int t1 = __builtin_amdgcn_cvt_pk_fp8_f32(f[4], f[5], 0, false);
    t1     = __builtin_amdgcn_cvt_pk_fp8_f32(f[6], f[7], t1, true);
    uint2 r; r.x = (unsigned)t0; r.y = (unsigned)t1;
    return r;
}
__device__ __forceinline__ void gload_lds16(const u16* gsrc, u16* lds_dst){
    __builtin_amdgcn_global_load_lds((const __attribute__((address_space(1))) unsigned int*)gsrc,
                                     (__attribute__((address_space(3))) unsigned int*)lds_dst,
                                     16, 0, 0);
}
// 16B-slot swizzle: q ^ (row&3) ^ ((row>>2)&3) — read side resolves to
// SWZ(quad,lm) independent of mi/wm (contribute 0 mod 4 to both XOR terms).
#define SWZ(q,row) ((q) ^ ((row)&3) ^ (((row)>>2)&3))

// ======================= CSR build =======================
__global__ void hist_k(const int* __restrict__ ei0, const int* __restrict__ ei1,
                       int* __restrict__ cnt){
    int e = blockIdx.x*256 + threadIdx.x;
    if (e < TE){
        int dst = (e < EE) ? ei0[EE + e] : ei1[EE + (e - EE)];
        atomicAdd(&cnt[dst], 1);
    }
}
__global__ void scan_block_k(const int* __restrict__ cnt, int* __restrict__ incl,
                             int* __restrict__ bsum){
    __shared__ int tmp[256];
    int tid = threadIdx.x;
    int i = blockIdx.x*256 + tid;
    int v = (i < NN) ? cnt[i] : 0;
    tmp[tid] = v;
    __syncthreads();
    for (int d=1; d<256; d<<=1){
        int t = (tid>=d) ? tmp[tid-d] : 0;
        __syncthreads();
        tmp[tid] += t;
        __syncthreads();
    }
    if (i < NN) incl[i] = tmp[tid];
    if (tid == 255) bsum[blockIdx.x] = tmp[255];
}
// fused: per-block exclusive prefix of bsum computed in-kernel (saves a dispatch)
__global__ void finalize_rowptr_k(const int* __restrict__ cnt, const int* __restrict__ incl,
                                  const int* __restrict__ bsum, int* __restrict__ row_ptr){
    __shared__ int wsum[4];
    int tid = threadIdx.x;
    int bid = blockIdx.x;
    int v = (tid < bid) ? bsum[tid] : 0;      // bid <= 78 < 128
    #pragma unroll
    for (int d=1; d<64; d<<=1) v += __shfl_xor(v, d);
    if ((tid & 63) == 0) wsum[tid >> 6] = v;
    __syncthreads();
    int bpre = wsum[0] + wsum[1] + wsum[2] + wsum[3];
    int i = bid*256 + tid;
    if (i < NN) row_ptr[i] = incl[i] - cnt[i] + bpre;
    if (i == NN) row_ptr[NN] = TE;
}
// stores the final kv-row index rel*NN+src per CSR slot
__global__ void scatter_k(const int* __restrict__ ei0, const int* __restrict__ ei1,
                          const int* __restrict__ row_ptr, int* __restrict__ cursor,
                          int* __restrict__ epk){
    int e = blockIdx.x*256 + threadIdx.x;
    if (e < TE){
        int src, dst, rel;
        if (e < EE){ src = ei0[e]; dst = ei0[EE+e]; rel = 0; }
        else { int ee=e-EE; src = ei1[ee]; dst = ei1[EE+ee]; rel = 1; }
        int pos = atomicAdd(&cursor[dst], 1);
        epk[row_ptr[dst] + pos] = rel*NN + src;
    }
}

// ======================= fused weight/input prep (one dispatch) =======================
__global__ void prep_k(const float* __restrict__ kqv_w, const float* __restrict__ kqv_b,
                       const float* __restrict__ krel, const float* __restrict__ vrel,
                       const float* __restrict__ prel, const float* __restrict__ out_w,
                       const float* __restrict__ x,
                       u16* __restrict__ Wt, u16* __restrict__ xbf, u16* __restrict__ Wto,
                       float* __restrict__ bias5, float* __restrict__ sc5,
                       int* __restrict__ cnt, int* __restrict__ cursor){
    int b = blockIdx.x;
    int tid = threadIdx.x;
    if (b < 1024){
        // q columns: straight transpose into k-panel layout
        int l = b >> 8, n = b & 255;
        int k = tid;
        const float* W = kqv_w + (size_t)l*196608;     // [256][768]
        float val = W[k*768 + 256 + n];
        Wt[(size_t)l*327680 + (size_t)(k>>5)*BPAN + n*32 + (k&31)] = f2bf(val);
    } else if (b < 1152){
        // relation fold: block per (l, g=isv*2+r, h); Rm staged in LDS once
        int b2 = b - 1024;
        int l = b2 >> 5;
        int g = (b2 >> 3) & 3;
        int h = b2 & 7;
        int r = g & 1, isv = g >> 1;
        __shared__ float Rs[32*36];
        const float* Rm = (isv ? vrel : krel) + ((size_t)l*2 + r)*8192 + h*1024;
        #pragma unroll
        for (int j=0; j<4; ++j){
            int idx = tid + 256*j;
            Rs[(idx>>5)*36 + (idx&31)] = Rm[idx];
        }
        __syncthreads();
        int base = isv ? 512 : 0;
        const float* W = kqv_w + (size_t)l*196608 + (size_t)tid*768 + base + h*32;
        float w[32];
        #pragma unroll 8
        for (int d=0; d<32; ++d) w[d] = W[d];
        f32x4 acc4[8];
        #pragma unroll
        for (int fb=0; fb<8; ++fb) acc4[fb] = (f32x4){0.f,0.f,0.f,0.f};
        for (int d=0; d<32; ++d){
            float wd = w[d];
            f32x4 wv = (f32x4){wd,wd,wd,wd};
            #pragma unroll
            for (int fb=0; fb<8; ++fb){
                f32x4 rv = *(const f32x4*)&Rs[d*36 + fb*4];
                acc4[fb] += wv * rv;
            }
        }
        int nb = 256 + g*256 + h*32;
        size_t wbase = (size_t)l*327680 + (size_t)(tid>>5)*BPAN + (size_t)(tid&31);
        #pragma unroll
        for (int fb=0; fb<8; ++fb)
            #pragma unroll
            for (int e=0; e<4; ++e)
                Wt[wbase + (size_t)(nb + fb*4 + e)*32] = f2bf(acc4[fb][e]);
    } else if (b < 3652){
        int idx = (b-1152)*256 + tid;                  // 640000 (8 elems each)
        int e = idx*8;
        int row = e >> 8, col = e & 255;
        const float4* xp = (const float4*)x;
        float4 a = xp[(size_t)idx*2], bb = xp[(size_t)idx*2+1];
        uint4 o;
        o.x = (unsigned)f2bf(a.x) | ((unsigned)f2bf(a.y)<<16);
        o.y = (unsigned)f2bf(a.z) | ((unsigned)f2bf(a.w)<<16);
        o.z = (unsigned)f2bf(bb.x) | ((unsigned)f2bf(bb.y)<<16);
        o.w = (unsigned)f2bf(bb.z) | ((unsigned)f2bf(bb.w)<<16);
        *(uint4*)&xbf[(size_t)(col>>5)*APAN + (size_t)row*32 + (col&31)] = o;
    } else if (b < 4676){
        int idx = (b-3652)*256 + tid;                  // 4*256*256
        int k = idx & 255;
        int n = (idx >> 8) & 255;
        int l = idx >> 16;
        Wto[(size_t)l*65536 + (size_t)(k>>5)*OPAN + n*32 + (k&31)] =
            f2bf(out_w[(size_t)l*65536 + k*256 + n]);
    } else if (b < 4696){
        int idx = (b-4676)*256 + tid;                  // 4*1280 exact
        int n = idx % 1280, l = idx / 1280;
        const float* B = kqv_b + l*768;
        float val, scl = 1.f;
        if (n < 256) val = B[256+n];
        else {
            int g = (n-256) >> 8;
            int r = g & 1, isv = g >> 1;
            int c = (n-256) & 255;
            int h = c >> 5, f = c & 31;
            const float* Rm = (isv ? vrel : krel) + ((size_t)l*2 + r)*8192 + h*1024;
            int base = isv ? 512 : 0;
            float a = 0.f;
            for (int d=0; d<32; ++d) a += B[base + h*32 + d] * Rm[d*32 + f];
            val = a;
            if (!isv) scl = prel[l*16 + r*8 + h] * 0.17677669529663687f;
        }
        bias5[idx] = val;
        sc5[idx] = scl;
    } else {
        // zero cnt + cursor (replaces hipMemsetAsync): 2 x 5000 int4
        int idx = (b-4696)*256 + tid;
        int4 z; z.x = 0; z.y = 0; z.z = 0; z.w = 0;
        if (idx < 5000)       ((int4*)cnt)[idx] = z;
        else if (idx < 10000) ((int4*)cursor)[idx-5000] = z;
    }
}

// ======================= K1: 5-output MFMA GEMM (BK=64, XCD-clustered) =========
// v10: B read DIRECTLY from global (Wt5 = 640KB/layer, L2-resident, reused by
// all 157 row-tiles — don't LDS-stage what L2 fits). LDS = A staging 16KB ||
// Cs16 16.9KB -> ~17KB -> 8 blocks/CU (32 waves, wave cap; was 5 blocks).
// B fragment reads are wave-coalesced (16 rows x 64B = 1KB contiguous) and
// independent of the staging barrier, so the compiler can hoist them.
__global__ __launch_bounds__(256) void gemm5_k(const u16* __restrict__ A,
        const u16* __restrict__ Wt, const float* __restrict__ biasp,
        const float* __restrict__ sc5p,
        u16* __restrict__ qb, u8* __restrict__ kvb){
    int L = blockIdx.x;
    int xcd = L & 7;
    int t = L >> 3;                  // 0..199
    int ytile = xcd*20 + t/10;       // 0..159
    int xtile = t % 10;
    if (ytile >= 157) return;        // uniform per block (before any barrier)
    int col0 = xtile * 128;
    int row0 = ytile * 128;

    __shared__ __align__(16) char smem[16896];   // As 16K || Cs16 16.9K (aliased)
    u16* As = (u16*)smem;                        // 2 panels x 4096 u16
    u16* Cs16 = (u16*)smem;                      // 128*66 bf16 (post-K-loop)
    int tid = threadIdx.x;
    int w = tid >> 6, lane = tid & 63;
    int wm = w & 1, wn = w >> 1;
    f32x4 acc[4][4];
    #pragma unroll
    for (int i=0;i<4;++i)
        #pragma unroll
        for (int j=0;j<4;++j) acc[i][j] = (f32x4){0.f,0.f,0.f,0.f};

    int lm = lane & 15, quad = lane >> 4;
    int kq0 = SWZ(quad, lm);
    int aoff = (wm*64 + lm)*32 + kq0*8;
    // B direct-read base: lane (lm,quad) reads col (col0+wn*64+lm), k-chunk quad
    const u16* Bp = Wt + (size_t)(col0 + wn*64 + lm)*32 + quad*8;

    for (int kk = 0; kk < 4; ++kk){
        #pragma unroll
        for (int hf = 0; hf < 2; ++hf){
            int pan = kk*2 + hf;
            #pragma unroll
            for (int it = 0; it < 2; ++it){
                int s = w*128 + it*64 + lane;      // 16B slot id (0..511)
                int row = s >> 2, q0 = s & 3;
                int kq = SWZ(q0, row);             // write-side swizzle via source addr
                gload_lds16(&A[(size_t)pan*APAN + (size_t)(row0+row)*32 + kq*8],
                            &As[(size_t)(hf*4096) + (size_t)(w*128 + it*64)*8]);
            }
        }
        __syncthreads();
        #pragma unroll
        for (int hf = 0; hf < 2; ++hf){
            int pan = kk*2 + hf;
            const u16* Bpp = Bp + (size_t)pan*BPAN;
            bf16x8 af[4], bfr[4];
            #pragma unroll
            for (int ni=0; ni<4; ++ni) bfr[ni] = *(const bf16x8*)(Bpp + ni*512);
            #pragma unroll
            for (int mi=0; mi<4; ++mi) af[mi]  = *(bf16x8*)&As[hf*4096 + aoff + mi*512];
            #pragma unroll
            for (int mi=0; mi<4; ++mi)
                #pragma unroll
                for (int ni=0; ni<4; ++ni)
                    acc[mi][ni] = __builtin_amdgcn_mfma_f32_16x16x32_bf16(af[mi], bfr[ni], acc[mi][ni], 0,0,0);
        }
        __syncthreads();    // last iteration also fences As before Cs16 aliasing
    }

    int bufi = col0 >> 8;   // 0:q 1:kr0 2:kr1 3:vr0 4:vr1 (uniform per block)
    int cbase = col0 & 255;
    float bvv[4], scv[4];
    #pragma unroll
    for (int ni=0; ni<4; ++ni){
        bvv[ni] = biasp[col0 + wn*64 + ni*16 + lm];
        scv[ni] = sc5p [col0 + wn*64 + ni*16 + lm];
    }

    int rowl_s = tid >> 3;              // 0..31
    int col8   = tid & 7;               // 0..7 (8 lcols each)
    int gcb    = (col8 >> 2)*64 + (col8 & 3)*8;

    #pragma unroll
    for (int p=0; p<2; ++p){
        if (p) __syncthreads();
        #pragma unroll
        for (int nj=0; nj<2; ++nj){
            int ni = p*2 + nj;
            int lcol = wn*32 + nj*16 + lm;
            #pragma unroll
            for (int mi=0; mi<4; ++mi){
                #pragma unroll
                for (int t2=0; t2<4; ++t2){
                    int lr = wm*64 + mi*16 + quad*4 + t2;
                    Cs16[lr*66 + lcol] = f2bf((acc[mi][ni][t2] + bvv[ni]) * scv[ni]);
                }
            }
        }
        __syncthreads();
        int cw = cbase + gcb + p*32;
        #pragma unroll
        for (int it=0; it<4; ++it){
            int rl = rowl_s + it*32;
            int r = row0 + rl;
            if (r < NN){
                // 4x u32 reads (4B-aligned; row stride 132B)
                const unsigned* src = (const unsigned*)Cs16 + (size_t)rl*33 + col8*4;
                unsigned v0 = src[0], v1 = src[1], v2 = src[2], v3 = src[3];
                if (bufi == 0){
                    uint4 o; o.x = v0; o.y = v1; o.z = v2; o.w = v3;
                    *(uint4*)&qb[(size_t)r*256 + cw] = o;
                } else {
                    float cf[8];
                    cf[0]=bf2f(v0&0xffffu); cf[1]=bf2f(v0>>16);
                    cf[2]=bf2f(v1&0xffffu); cf[3]=bf2f(v1>>16);
                    cf[4]=bf2f(v2&0xffffu); cf[5]=bf2f(v2>>16);
                    cf[6]=bf2f(v3&0xffffu); cf[7]=bf2f(v3>>16);
                    uint2 o = enc8_fp8(cf);
                    if (bufi <= 2){
                        int rel = bufi - 1;
                        *(uint2*)&kvb[(size_t)(rel*NN + r)*KVSTRIDE + cw*2] = o;
                    } else {
                        int rel = bufi - 3;
                        *(uint2*)&kvb[(size_t)(rel*NN + r)*KVSTRIDE + cw*2 + 8] = o;
                    }
                }
            }
        }
    }
}

// ======================= K2: split-wave CSR attention, online softmax ==============
// kv row: 32 chunks of [kr 8B | vr 8B] -> ONE uint4 gather per edge per lane.
// round-2 proven version (depth-3 prefetch).
__global__ __launch_bounds__(256) void attn_k(const u16* __restrict__ qb,
        const u8* __restrict__ kvb,
        const int* __restrict__ row_ptr, const int* __restrict__ epk,
        u16* __restrict__ A2){
    int wv = threadIdx.x >> 6, lane = threadIdx.x & 63;
    int node = blockIdx.x*4 + wv;
    int l32 = lane & 31;
    int half = lane >> 5;
    int start = row_ptr[node], end = row_ptr[node+1];
    f32x2 qf[4];
    {
        uint4 qr = *(const uint4*)&qb[(size_t)node*256 + l32*8];
        qf[0] = (f32x2){__uint_as_float(qr.x<<16), __uint_as_float(qr.x&0xffff0000u)};
        qf[1] = (f32x2){__uint_as_float(qr.y<<16), __uint_as_float(qr.y&0xffff0000u)};
        qf[2] = (f32x2){__uint_as_float(qr.z<<16), __uint_as_float(qr.z&0xffff0000u)};
        qf[3] = (f32x2){__uint_as_float(qr.w<<16), __uint_as_float(qr.w&0xffff0000u)};
    }
    float m = -1e30f, s = 0.f;
    f32x2 acc[4];
    #pragma unroll
    for (int j=0;j<4;++j) acc[j] = (f32x2){0.f,0.f};

    int i0 = start + half;
    uint4 c0={0,0,0,0}, c1={0,0,0,0}, c2={0,0,0,0};
    if (i0     < end) c0 = *(const uint4*)&kvb[(size_t)epk[i0  ]*KVSTRIDE + l32*16];
    if (i0 + 2 < end) c1 = *(const uint4*)&kvb[(size_t)epk[i0+2]*KVSTRIDE + l32*16];
    if (i0 + 4 < end) c2 = *(const uint4*)&kvb[(size_t)epk[i0+4]*KVSTRIDE + l32*16];
    int pk = (i0 + 6 < end) ? epk[i0+6] : 0;

    for (int i = i0; i < end; i += 2){
        uint4 cc = c0; c0 = c1; c1 = c2;
        if (i + 6 < end)                       // refill depth-3 slot
            c2 = *(const uint4*)&kvb[(size_t)pk*KVSTRIDE + l32*16];
        if (i + 8 < end) pk = epk[i+8];        // index 4 deep
        f32x2 kf0 = __builtin_amdgcn_cvt_pk_f32_fp8(cc.x, false);
        f32x2 kf1 = __builtin_amdgcn_cvt_pk_f32_fp8(cc.x, true);
        f32x2 kf2 = __builtin_amdgcn_cvt_pk_f32_fp8(cc.y, false);
        f32x2 kf3 = __builtin_amdgcn_cvt_pk_f32_fp8(cc.y, true);
        f32x2 p2 = qf[0]*kf0 + qf[1]*kf1 + qf[2]*kf2 + qf[3]*kf3;
        float p = p2.x + p2.y;
        p += __shfl_xor(p, 1);
        p += __shfl_xor(p, 2);                 // logit (prel/sqrt folded into kr)
        float mo = m;
        m = fmaxf(m, p);
        float sc = __expf(mo - m);
        float pe = __expf(p - m);
        s = s*sc + pe;
        f32x2 vf0 = __builtin_amdgcn_cvt_pk_f32_fp8(cc.z, false);
        f32x2 vf1 = __builtin_amdgcn_cvt_pk_f32_fp8(cc.z, true);
        f32x2 vf2 = __builtin_amdgcn_cvt_pk_f32_fp8(cc.w, false);
        f32x2 vf3 = __builtin_amdgcn_cvt_pk_f32_fp8(cc.w, true);
        f32x2 sc2 = (f32x2){sc,sc}, pe2 = (f32x2){pe,pe};
        acc[0] = acc[0]*sc2 + pe2*vf0;
        acc[1] = acc[1]*sc2 + pe2*vf1;
        acc[2] = acc[2]*sc2 + pe2*vf2;
        acc[3] = acc[3]*sc2 + pe2*vf3;
    }
    // merge the two halves' online-softmax states (m=-1e30: no inf-inf NaN)
    float mO = __shfl_xor(m, 32);
    float mA = fmaxf(m, mO);
    float eS = __expf(m - mA);
    float sh = s * eS;
    float sA = sh + __shfl_xor(sh, 32);
    float rs = 1.f / fmaxf(sA, 1e-16f);
    float oA[8];
    #pragma unroll
    for (int j=0;j<4;++j){
        f32x2 a = acc[j] * (f32x2){eS,eS};
        oA[2*j]   = a.x + __shfl_xor(a.x, 32);
        oA[2*j+1] = a.y + __shfl_xor(a.y, 32);
    }
    if (half == 0){
        u16 o[8];
        #pragma unroll
        for (int j=0;j<8;++j) o[j] = f2bf(gelu_exact(oA[j]*rs));
        uint4 ov;
        ov.x = (unsigned)o[0] | ((unsigned)o[1]<<16);
        ov.y = (unsigned)o[2] | ((unsigned)o[3]<<16);
        ov.z = (unsigned)o[4] | ((unsigned)o[5]<<16);
        ov.w = (unsigned)o[6] | ((unsigned)o[7]<<16);
        int c0b = l32*8;
        *(uint4*)&A2[(size_t)(c0b>>5)*APAN + (size_t)node*32 + (c0b&31)] = ov;
    }
}

// ======================= K3a: out GEMM + skip + relu + LN (layers 0-2) ===========
// round-2 structure (32-row tiles, BK=64) + conflict-free fragment swizzle.
__global__ __launch_bounds__(256) void gemmOln_k(const u16* __restrict__ A,
        const u16* __restrict__ Wt, const float* __restrict__ bias,
        const float* __restrict__ h_in, const float* __restrict__ skip_l,
        const float* __restrict__ g, const float* __restrict__ b,
        float* __restrict__ h_out, u16* __restrict__ hbf){
    __shared__ __align__(16) char smem[36864];   // As 4KB + Bs 32KB; LN partials alias
    u16* As = (u16*)smem;                        // 2 panels x 32 rows x 32 k = 2048 u16
    u16* Bs = (u16*)(smem + 4096);               // 2 panels x 256 cols x 32 k = 16384 u16
    float* part_s = (float*)smem;                // [32][66]
    float* part_q = part_s + 32*66;              // [32][66]
    float* mu_s   = part_q + 32*66;              // [32]
    float* rstd_s = mu_s + 32;                   // [32]
    int tid = threadIdx.x;
    int w = tid >> 6, lane = tid & 63;
    int row0 = blockIdx.x * 32;
    f32x4 acc[2][4];
    #pragma unroll
    for (int i=0;i<2;++i)
        #pragma unroll
        for (int j=0;j<4;++j) acc[i][j] = (f32x4){0.f,0.f,0.f,0.f};

    int lm = lane & 15, quad = lane >> 4;
    int kq0 = SWZ(quad, lm);
    int aoff = lm*32 + kq0*8;
    int boff = (w*64 + lm)*32 + kq0*8;

    for (int kk2 = 0; kk2 < 4; ++kk2){
        {
            int s = tid;                       // 256 slots = 2 halves x 32 rows x 4
            int hf = s >> 7;
            int s7 = s & 127;
            int row = s7 >> 2, q0 = s7 & 3;
            int kq = SWZ(q0, row);
            gload_lds16(&A[(size_t)(kk2*2+hf)*APAN + (size_t)(row0+row)*32 + kq*8],
                        &As[(size_t)(w*64)*8]);
        }
        #pragma unroll
        for (int it = 0; it < 8; ++it){        // 2048 slots = 2 halves x 256 n-rows x 4
            int s = it*256 + tid;
            int hf = s >> 10;
            int s10 = s & 1023;
            int row = s10 >> 2, q0 = s10 & 3;
            int kq = SWZ(q0, row);
            gload_lds16(&Wt[(size_t)(kk2*2+hf)*OPAN + (size_t)row*32 + kq*8],
                        &Bs[(size_t)(it*256 + w*64)*8]);
        }
        __syncthreads();
        #pragma unroll
        for (int hf = 0; hf < 2; ++hf){
            bf16x8 af[2], bfr[4];
            #pragma unroll
            for (int mi=0; mi<2; ++mi) af[mi]  = *(bf16x8*)&As[hf*1024 + aoff + mi*512];
            #pragma unroll
            for (int ni=0; ni<4; ++ni) bfr[ni] = *(bf16x8*)&Bs[hf*8192 + boff + ni*512];
            #pragma unroll
            for (int mi=0; mi<2; ++mi)
                #pragma unroll
                for (int ni=0; ni<4; ++ni)
                    acc[mi][ni] = __builtin_amdgcn_mfma_f32_16x16x32_bf16(af[mi], bfr[ni], acc[mi][ni], 0,0,0);
        }
        __syncthreads();    // also fences As/Bs before LN-partial aliasing
    }

    float sskip = 1.f/(1.f+__expf(-skip_l[0]));
    float osk = 1.f - sskip;
    float bv[4], gv[4], bbv[4];
    #pragma unroll
    for (int ni=0; ni<4; ++ni){
        int colg = w*64 + ni*16 + lm;
        bv[ni]  = bias[colg];
        gv[ni]  = g[colg];
        bbv[ni] = b[colg];
    }
    #pragma unroll
    for (int mi=0; mi<2; ++mi){
        #pragma unroll
        for (int t=0; t<4; ++t){
            int lr = mi*16 + quad*4 + t;       // 0..31
            int r = row0 + lr;                 // always < NN (625*32 = 20000)
            float ps = 0.f, pq = 0.f;
            #pragma unroll
            for (int ni=0; ni<4; ++ni){
                int colg = w*64 + ni*16 + lm;
                float hv = h_in[(size_t)r*256 + colg];
                float val = sskip*(acc[mi][ni][t] + bv[ni]) + osk*hv;
                val = fmaxf(val, 0.f);
                acc[mi][ni][t] = val;
                ps += val; pq += val*val;
            }
            part_s[lr*66 + w*16 + lm] = ps;
            part_q[lr*66 + w*16 + lm] = pq;
        }
    }
    __syncthreads();
    if (tid < 32){
        float S = 0.f, Q = 0.f;
        #pragma unroll 8
        for (int t2=0; t2<64; ++t2){
            S += part_s[tid*66 + t2];
            Q += part_q[tid*66 + t2];
        }
        float mu = S * (1.f/256.f);
        float var = Q * (1.f/256.f) - mu*mu;
        mu_s[tid] = mu;
        rstd_s[tid] = rsqrtf(var + 1e-5f);
    }
    __syncthreads();
    #pragma unroll
    for (int mi=0; mi<2; ++mi){
        #pragma unroll
        for (int t=0; t<4; ++t){
            int lr = mi*16 + quad*4 + t;
            int r = row0 + lr;
            float mu = mu_s[lr], rstd = rstd_s[lr];
            #pragma unroll
            for (int ni=0; ni<4; ++ni){
                int colg = w*64 + ni*16 + lm;
                float o = (acc[mi][ni][t] - mu)*rstd*gv[ni] + bbv[ni];
                h_out[(size_t)r*256 + colg] = o;
                hbf[(size_t)(colg>>5)*APAN + (size_t)r*32 + (colg&31)] = f2bf(o);
            }
        }
    }
}

// ======================= K3b: out GEMM + skip blend (final layer) =======================
// 64x128 tiles -> grid (313,2); conflict-free fragment swizzle.
__global__ __launch_bounds__(256) void gemmO_k(const u16* __restrict__ A,
        const u16* __restrict__ Wt, const float* __restrict__ bias,
        const float* __restrict__ h_in, const float* __restrict__ skip_l,
        float* __restrict__ outp){
    __shared__ u16 As[2048];       // 64 rows x 32 k
    __shared__ u16 Bs[4096];       // 128 cols x 32 k
    int tid = threadIdx.x;
    int w = tid >> 6, lane = tid & 63;
    int row0 = blockIdx.x * 64;
    int col0 = blockIdx.y * 128;
    int wm = w & 1, wn = w >> 1;
    f32x4 acc[2][4];
    #pragma unroll
    for (int i=0;i<2;++i)
        #pragma unroll
        for (int j=0;j<4;++j) acc[i][j] = (f32x4){0.f,0.f,0.f,0.f};

    int lm = lane & 15, quad = lane >> 4;
    int kq0 = SWZ(quad, lm);
    int aoff = (wm*32 + lm)*32 + kq0*8;
    int boff = (wn*64 + lm)*32 + kq0*8;

    for (int kk = 0; kk < 8; ++kk){
        {
            int s = tid;                       // 256 slots = 64 rows x 4
            int row = s >> 2, q0 = s & 3;
            int kq = SWZ(q0, row);
            gload_lds16(&A[(size_t)kk*APAN + (size_t)(row0+row)*32 + kq*8],
                        &As[(size_t)(w*64)*8]);
        }
        #pragma unroll
        for (int it = 0; it < 2; ++it){        // 512 slots = 128 n-rows x 4
            int s = it*256 + tid;
            int row = s >> 2, q0 = s & 3;
            int kq = SWZ(q0, row);
            gload_lds16(&Wt[(size_t)kk*OPAN + (size_t)(col0+row)*32 + kq*8],
                        &Bs[(size_t)(it*256 + w*64)*8]);
        }
        __syncthreads();
        bf16x8 af[2], bfr[4];
        #pragma unroll
        for (int mi=0; mi<2; ++mi) af[mi]  = *(bf16x8*)&As[aoff + mi*512];
        #pragma unroll
        for (int ni=0; ni<4; ++ni) bfr[ni] = *(bf16x8*)&Bs[boff + ni*512];
        #pragma unroll
        for (int mi=0; mi<2; ++mi)
            #pragma unroll
            for (int ni=0; ni<4; ++ni)
                acc[mi][ni] = __builtin_amdgcn_mfma_f32_16x16x32_bf16(af[mi], bfr[ni], acc[mi][ni], 0,0,0);
        __syncthreads();
    }
    float s = 1.f/(1.f+expf(-skip_l[0]));
    float os = 1.f - s;
    #pragma unroll
    for (int ni=0; ni<4; ++ni){
        int colg = col0 + wn*64 + ni*16 + lm;
        float bv = bias[colg];
        #pragma unroll
        for (int mi=0; mi<2; ++mi){
            #pragma unroll
            for (int t=0; t<4; ++t){
                int r = row0 + wm*32 + mi*16 + quad*4 + t;
                if (r < NN)
                    outp[(size_t)r*256 + colg] =
                        s*(acc[mi][ni][t] + bv) + os*h_in[(size_t)r*256 + colg];
            }
        }
    }
}

// ======================= host =======================
extern "C" void kernel_launch(void* const* d_in, const int* in_sizes, int n_in,
                              void* d_out, int out_size, void* d_ws, size_t ws_size,
                              hipStream_t stream){
    (void)in_sizes; (void)n_in; (void)out_size; (void)ws_size;
    const float* x     = (const float*)d_in[0];
    const int*   ei0   = (const int*)d_in[1];
    const int*   ei1   = (const int*)d_in[2];
    const float* kqv_w = (const float*)d_in[3];
    const float* kqv_b = (const float*)d_in[4];
    const float* out_w = (const float*)d_in[5];
    const float* out_b = (const float*)d_in[6];
    const float* skip  = (const float*)d_in[7];
    const float* krel  = (const float*)d_in[8];
    const float* vrel  = (const float*)d_in[9];
    const float* prel  = (const float*)d_in[10];
    const float* ln_g  = (const float*)d_in[11];
    const float* ln_b  = (const float*)d_in[12];
    float* outp = (float*)d_out;

    char* wp = (char*)d_ws;
    auto alloc = [&](size_t bytes)->void*{
        void* p = wp; wp += (bytes + 255) & ~(size_t)255; return p;
    };
    float* hA    = (float*)alloc((size_t)NN*CC*4);
    float* hB    = (float*)alloc((size_t)NN*CC*4);
    u16*   xbf   = (u16*)alloc((size_t)NPAD*CC*2);   // k-panel layout
    u16*   hbf   = (u16*)alloc((size_t)NPAD*CC*2);   // k-panel layout
    u16*   A2    = (u16*)alloc((size_t)NPAD*CC*2);   // k-panel layout
    u16*   qb    = (u16*)alloc((size_t)NN*CC*2);
    u8*    kvb   = (u8*)alloc((size_t)2*NN*KVSTRIDE);   // [rel*NN+node][32 x (kr8|vr8)]
    u16*   Wt5   = (u16*)alloc((size_t)4*1280*256*2);   // k-panel layout
    u16*   Wto   = (u16*)alloc((size_t)4*256*256*2);    // k-panel layout
    float* bias5 = (float*)alloc((size_t)4*1280*4);
    float* sc5   = (float*)alloc((size_t)4*1280*4);
    int* cnt     = (int*)alloc((size_t)NN*4);
    int* cursor  = (int*)alloc((size_t)NN*4);
    int* incl    = (int*)alloc((size_t)NN*4);
    int* row_ptr = (int*)alloc((size_t)(NN+1)*4);
    int* bsum    = (int*)alloc(128*4);
    int* epk     = (int*)alloc((size_t)TE*4);

    // fused prep (weights + input cast + cnt/cursor zero) — one dispatch
    prep_k<<<4736,256,0,stream>>>(kqv_w, kqv_b, krel, vrel, prel, out_w, x,
                                  Wt5, xbf, Wto, bias5, sc5, cnt, cursor);

    // CSR build (cnt/cursor zeroed by prep_k on the same stream)
    hist_k<<<1250,256,0,stream>>>(ei0, ei1, cnt);
    scan_block_k<<<79,256,0,stream>>>(cnt, incl, bsum);
    finalize_rowptr_k<<<79,256,0,stream>>>(cnt, incl, bsum, row_ptr);
    scatter_k<<<1250,256,0,stream>>>(ei0, ei1, row_ptr, cursor, epk);

    const float* h_in = x;
    const u16*   Ain  = xbf;
    float* houts[4] = {hA, hB, hA, outp};
    for (int l=0; l<4; ++l){
        gemm5_k<<<1600,256,0,stream>>>(Ain, Wt5 + (size_t)l*327680,
                bias5 + l*1280, sc5 + l*1280, qb, kvb);
        attn_k<<<5000,256,0,stream>>>(qb, kvb, row_ptr, epk, A2);
        if (l < 3){
            gemmOln_k<<<625,256,0,stream>>>(A2, Wto + (size_t)l*65536,
                    out_b + l*256, h_in, skip + l, ln_g + l*256, ln_b + l*256,
                    houts[l], hbf);
        } else {
            gemmO_k<<<dim3(313,2),256,0,stream>>>(A2, Wto + (size_t)l*65536,
                    out_b + l*256, h_in, skip + l, outp);
        }
        h_in = houts[l];
        Ain = hbf;
    }
}

// Round 13
// 331.168 us; speedup vs baseline: 1.0581x; 1.0581x over previous
//
#include <hip/hip_runtime.h>
#include <math.h>

#define NN 20000
#define NPAD 20096          // padded rows for unguarded MFMA staging (157*128)
#define CC 256
#define HH 8
#define EE 160000
#define TE 320000
#define KVSTRIDE 512        // bytes per kv row: 32 chunks of [kr 8B | vr 8B]
#define APAN ((size_t)NPAD*32)   // u16 elems per A-operand k-panel (xbf/hbf/A2)
#define BPAN 40960               // u16 elems per Wt5 k-panel (1280*32)
#define OPAN 8192                // u16 elems per Wto k-panel (256*32)

typedef unsigned short u16;
typedef unsigned char u8;
typedef __attribute__((ext_vector_type(8))) short bf16x8;
typedef __attribute__((ext_vector_type(4))) float f32x4;
typedef __attribute__((ext_vector_type(2))) float f32x2;

__device__ __forceinline__ float gelu_exact(float x){
    return 0.5f*x*(1.0f+erff(x*0.7071067811865476f));
}
__device__ __forceinline__ u16 f2bf(float f){
    unsigned u = __float_as_uint(f);
    unsigned r = (u + 0x7fffu + ((u >> 16) & 1u)) >> 16;
    return (u16)r;
}
__device__ __forceinline__ float bf2f(unsigned s){
    return __uint_as_float(s << 16);
}
__device__ __forceinline__ uint2 enc8_fp8(const float* f){
    int t0 = __builtin_amdgcn_cvt_pk_fp8_f32(f[0], f[1], 0, false);
    t0     = __builtin_amdgcn_cvt_pk_fp8_f32(f[2], f[3], t0, true);
    int t1 = __builtin_amdgcn_cvt_pk_fp8_f32(f[4], f[5], 0, false);
    t1     = __builtin_amdgcn_cvt_pk_fp8_f32(f[6], f[7], t1, true);
    uint2 r; r.x = (unsigned)t0; r.y = (unsigned)t1;
    return r;
}
__device__ __forceinline__ void gload_lds16(const u16* gsrc, u16* lds_dst){
    __builtin_amdgcn_global_load_lds((const __attribute__((address_space(1))) unsigned int*)gsrc,
                                     (__attribute__((address_space(3))) unsigned int*)lds_dst,
                                     16, 0, 0);
}
// 16B-slot swizzle: q ^ (row&3) ^ ((row>>2)&3) — read side resolves to
// SWZ(quad,lm) independent of mi/wm (contribute 0 mod 4 to both XOR terms).
#define SWZ(q,row) ((q) ^ ((row)&3) ^ (((row)>>2)&3))

// ======================= CSR build =======================
__global__ void hist_k(const int* __restrict__ ei0, const int* __restrict__ ei1,
                       int* __restrict__ cnt){
    int e = blockIdx.x*256 + threadIdx.x;
    if (e < TE){
        int dst = (e < EE) ? ei0[EE + e] : ei1[EE + (e - EE)];
        atomicAdd(&cnt[dst], 1);
    }
}
__global__ void scan_block_k(const int* __restrict__ cnt, int* __restrict__ incl,
                             int* __restrict__ bsum){
    __shared__ int tmp[256];
    int tid = threadIdx.x;
    int i = blockIdx.x*256 + tid;
    int v = (i < NN) ? cnt[i] : 0;
    tmp[tid] = v;
    __syncthreads();
    for (int d=1; d<256; d<<=1){
        int t = (tid>=d) ? tmp[tid-d] : 0;
        __syncthreads();
        tmp[tid] += t;
        __syncthreads();
    }
    if (i < NN) incl[i] = tmp[tid];
    if (tid == 255) bsum[blockIdx.x] = tmp[255];
}
// fused: per-block exclusive prefix of bsum computed in-kernel (saves a dispatch)
__global__ void finalize_rowptr_k(const int* __restrict__ cnt, const int* __restrict__ incl,
                                  const int* __restrict__ bsum, int* __restrict__ row_ptr){
    __shared__ int wsum[4];
    int tid = threadIdx.x;
    int bid = blockIdx.x;
    int v = (tid < bid) ? bsum[tid] : 0;      // bid <= 78 < 128
    #pragma unroll
    for (int d=1; d<64; d<<=1) v += __shfl_xor(v, d);
    if ((tid & 63) == 0) wsum[tid >> 6] = v;
    __syncthreads();
    int bpre = wsum[0] + wsum[1] + wsum[2] + wsum[3];
    int i = bid*256 + tid;
    if (i < NN) row_ptr[i] = incl[i] - cnt[i] + bpre;
    if (i == NN) row_ptr[NN] = TE;
}
// stores the final kv-row index rel*NN+src per CSR slot
__global__ void scatter_k(const int* __restrict__ ei0, const int* __restrict__ ei1,
                          const int* __restrict__ row_ptr, int* __restrict__ cursor,
                          int* __restrict__ epk){
    int e = blockIdx.x*256 + threadIdx.x;
    if (e < TE){
        int src, dst, rel;
        if (e < EE){ src = ei0[e]; dst = ei0[EE+e]; rel = 0; }
        else { int ee=e-EE; src = ei1[ee]; dst = ei1[EE+ee]; rel = 1; }
        int pos = atomicAdd(&cursor[dst], 1);
        epk[row_ptr[dst] + pos] = rel*NN + src;
    }
}

// ======================= fused weight/input prep (one dispatch) =======================
__global__ void prep_k(const float* __restrict__ kqv_w, const float* __restrict__ kqv_b,
                       const float* __restrict__ krel, const float* __restrict__ vrel,
                       const float* __restrict__ prel, const float* __restrict__ out_w,
                       const float* __restrict__ x,
                       u16* __restrict__ Wt, u16* __restrict__ xbf, u16* __restrict__ Wto,
                       float* __restrict__ bias5, float* __restrict__ sc5,
                       int* __restrict__ cnt, int* __restrict__ cursor){
    int b = blockIdx.x;
    int tid = threadIdx.x;
    if (b < 1024){
        // q columns: straight transpose into k-panel layout
        int l = b >> 8, n = b & 255;
        int k = tid;
        const float* W = kqv_w + (size_t)l*196608;     // [256][768]
        float val = W[k*768 + 256 + n];
        Wt[(size_t)l*327680 + (size_t)(k>>5)*BPAN + n*32 + (k&31)] = f2bf(val);
    } else if (b < 1152){
        // relation fold: block per (l, g=isv*2+r, h); Rm staged in LDS once
        int b2 = b - 1024;
        int l = b2 >> 5;
        int g = (b2 >> 3) & 3;
        int h = b2 & 7;
        int r = g & 1, isv = g >> 1;
        __shared__ float Rs[32*36];
        const float* Rm = (isv ? vrel : krel) + ((size_t)l*2 + r)*8192 + h*1024;
        #pragma unroll
        for (int j=0; j<4; ++j){
            int idx = tid + 256*j;
            Rs[(idx>>5)*36 + (idx&31)] = Rm[idx];
        }
        __syncthreads();
        int base = isv ? 512 : 0;
        const float* W = kqv_w + (size_t)l*196608 + (size_t)tid*768 + base + h*32;
        float w[32];
        #pragma unroll 8
        for (int d=0; d<32; ++d) w[d] = W[d];
        f32x4 acc4[8];
        #pragma unroll
        for (int fb=0; fb<8; ++fb) acc4[fb] = (f32x4){0.f,0.f,0.f,0.f};
        for (int d=0; d<32; ++d){
            float wd = w[d];
            f32x4 wv = (f32x4){wd,wd,wd,wd};
            #pragma unroll
            for (int fb=0; fb<8; ++fb){
                f32x4 rv = *(const f32x4*)&Rs[d*36 + fb*4];
                acc4[fb] += wv * rv;
            }
        }
        int nb = 256 + g*256 + h*32;
        size_t wbase = (size_t)l*327680 + (size_t)(tid>>5)*BPAN + (size_t)(tid&31);
        #pragma unroll
        for (int fb=0; fb<8; ++fb)
            #pragma unroll
            for (int e=0; e<4; ++e)
                Wt[wbase + (size_t)(nb + fb*4 + e)*32] = f2bf(acc4[fb][e]);
    } else if (b < 3652){
        int idx = (b-1152)*256 + tid;                  // 640000 (8 elems each)
        int e = idx*8;
        int row = e >> 8, col = e & 255;
        const float4* xp = (const float4*)x;
        float4 a = xp[(size_t)idx*2], bb = xp[(size_t)idx*2+1];
        uint4 o;
        o.x = (unsigned)f2bf(a.x) | ((unsigned)f2bf(a.y)<<16);
        o.y = (unsigned)f2bf(a.z) | ((unsigned)f2bf(a.w)<<16);
        o.z = (unsigned)f2bf(bb.x) | ((unsigned)f2bf(bb.y)<<16);
        o.w = (unsigned)f2bf(bb.z) | ((unsigned)f2bf(bb.w)<<16);
        *(uint4*)&xbf[(size_t)(col>>5)*APAN + (size_t)row*32 + (col&31)] = o;
    } else if (b < 4676){
        int idx = (b-3652)*256 + tid;                  // 4*256*256
        int k = idx & 255;
        int n = (idx >> 8) & 255;
        int l = idx >> 16;
        Wto[(size_t)l*65536 + (size_t)(k>>5)*OPAN + n*32 + (k&31)] =
            f2bf(out_w[(size_t)l*65536 + k*256 + n]);
    } else if (b < 4696){
        int idx = (b-4676)*256 + tid;                  // 4*1280 exact
        int n = idx % 1280, l = idx / 1280;
        const float* B = kqv_b + l*768;
        float val, scl = 1.f;
        if (n < 256) val = B[256+n];
        else {
            int g = (n-256) >> 8;
            int r = g & 1, isv = g >> 1;
            int c = (n-256) & 255;
            int h = c >> 5, f = c & 31;
            const float* Rm = (isv ? vrel : krel) + ((size_t)l*2 + r)*8192 + h*1024;
            int base = isv ? 512 : 0;
            float a = 0.f;
            for (int d=0; d<32; ++d) a += B[base + h*32 + d] * Rm[d*32 + f];
            val = a;
            if (!isv) scl = prel[l*16 + r*8 + h] * 0.17677669529663687f;
        }
        bias5[idx] = val;
        sc5[idx] = scl;
    } else {
        // zero cnt + cursor (replaces hipMemsetAsync): 2 x 5000 int4
        int idx = (b-4696)*256 + tid;
        int4 z; z.x = 0; z.y = 0; z.z = 0; z.w = 0;
        if (idx < 5000)       ((int4*)cnt)[idx] = z;
        else if (idx < 10000) ((int4*)cursor)[idx-5000] = z;
    }
}

// ======================= K1: 5-output MFMA GEMM (BK=64, XCD-clustered) =========
// v9 (measured best, round 11): round-2 structure + SWZ, Cs stored as bf16
// (128x66x2 = 16.9KB) so total LDS = 32768 exactly -> 5 blocks/CU.
// qb path: direct u32 copy (f2bf applied at Cs write). kvb: bf16->f32->fp8.
__global__ __launch_bounds__(256) void gemm5_k(const u16* __restrict__ A,
        const u16* __restrict__ Wt, const float* __restrict__ biasp,
        const float* __restrict__ sc5p,
        u16* __restrict__ qb, u8* __restrict__ kvb){
    int L = blockIdx.x;
    int xcd = L & 7;
    int t = L >> 3;                  // 0..199
    int ytile = xcd*20 + t/10;       // 0..159
    int xtile = t % 10;
    if (ytile >= 157) return;        // uniform per block (before any barrier)
    int col0 = xtile * 128;
    int row0 = ytile * 128;

    __shared__ __align__(16) char smem[32768];   // As 16K + Bs 16K; Cs16 16.9K aliases
    u16* As = (u16*)smem;                        // 8192 u16 (2 panels of 4096)
    u16* Bs = (u16*)(smem + 16384);              // 8192 u16
    u16* Cs16 = (u16*)smem;                      // 128*66 bf16 (aliases post-K-loop)
    int tid = threadIdx.x;
    int w = tid >> 6, lane = tid & 63;
    int wm = w & 1, wn = w >> 1;
    f32x4 acc[4][4];
    #pragma unroll
    for (int i=0;i<4;++i)
        #pragma unroll
        for (int j=0;j<4;++j) acc[i][j] = (f32x4){0.f,0.f,0.f,0.f};

    int lm = lane & 15, quad = lane >> 4;
    int kq0 = SWZ(quad, lm);
    int aoff = (wm*64 + lm)*32 + kq0*8;
    int boff = (wn*64 + lm)*32 + kq0*8;

    for (int kk = 0; kk < 4; ++kk){
        #pragma unroll
        for (int hf = 0; hf < 2; ++hf){
            int pan = kk*2 + hf;
            #pragma unroll
            for (int it = 0; it < 2; ++it){
                int s = w*128 + it*64 + lane;      // 16B slot id (0..511)
                int row = s >> 2, q0 = s & 3;
                int kq = SWZ(q0, row);             // write-side swizzle via source addr
                gload_lds16(&A [(size_t)pan*APAN + (size_t)(row0+row)*32 + kq*8],
                            &As[(size_t)(hf*4096) + (size_t)(w*128 + it*64)*8]);
                gload_lds16(&Wt[(size_t)pan*BPAN + (size_t)(col0+row)*32 + kq*8],
                            &Bs[(size_t)(hf*4096) + (size_t)(w*128 + it*64)*8]);
            }
        }
        __syncthreads();
        #pragma unroll
        for (int hf = 0; hf < 2; ++hf){
            bf16x8 af[4], bfr[4];
            #pragma unroll
            for (int mi=0; mi<4; ++mi) af[mi]  = *(bf16x8*)&As[hf*4096 + aoff + mi*512];
            #pragma unroll
            for (int ni=0; ni<4; ++ni) bfr[ni] = *(bf16x8*)&Bs[hf*4096 + boff + ni*512];
            #pragma unroll
            for (int mi=0; mi<4; ++mi)
                #pragma unroll
                for (int ni=0; ni<4; ++ni)
                    acc[mi][ni] = __builtin_amdgcn_mfma_f32_16x16x32_bf16(af[mi], bfr[ni], acc[mi][ni], 0,0,0);
        }
        __syncthreads();    // last iteration also fences As/Bs before Cs16 aliasing
    }

    int bufi = col0 >> 8;   // 0:q 1:kr0 2:kr1 3:vr0 4:vr1 (uniform per block)
    int cbase = col0 & 255;
    float bvv[4], scv[4];
    #pragma unroll
    for (int ni=0; ni<4; ++ni){
        bvv[ni] = biasp[col0 + wn*64 + ni*16 + lm];
        scv[ni] = sc5p [col0 + wn*64 + ni*16 + lm];
    }

    int rowl_s = tid >> 3;              // 0..31
    int col8   = tid & 7;               // 0..7 (8 lcols each)
    int gcb    = (col8 >> 2)*64 + (col8 & 3)*8;

    #pragma unroll
    for (int p=0; p<2; ++p){
        if (p) __syncthreads();
        #pragma unroll
        for (int nj=0; nj<2; ++nj){
            int ni = p*2 + nj;
            int lcol = wn*32 + nj*16 + lm;
            #pragma unroll
            for (int mi=0; mi<4; ++mi){
                #pragma unroll
                for (int t2=0; t2<4; ++t2){
                    int lr = wm*64 + mi*16 + quad*4 + t2;
                    Cs16[lr*66 + lcol] = f2bf((acc[mi][ni][t2] + bvv[ni]) * scv[ni]);
                }
            }
        }
        __syncthreads();
        int cw = cbase + gcb + p*32;
        #pragma unroll
        for (int it=0; it<4; ++it){
            int rl = rowl_s + it*32;
            int r = row0 + rl;
            if (r < NN){
                // 4x u32 reads (4B-aligned; row stride 132B)
                const unsigned* src = (const unsigned*)Cs16 + (size_t)rl*33 + col8*4;
                unsigned v0 = src[0], v1 = src[1], v2 = src[2], v3 = src[3];
                if (bufi == 0){
                    uint4 o; o.x = v0; o.y = v1; o.z = v2; o.w = v3;
                    *(uint4*)&qb[(size_t)r*256 + cw] = o;
                } else {
                    float cf[8];
                    cf[0]=bf2f(v0&0xffffu); cf[1]=bf2f(v0>>16);
                    cf[2]=bf2f(v1&0xffffu); cf[3]=bf2f(v1>>16);
                    cf[4]=bf2f(v2&0xffffu); cf[5]=bf2f(v2>>16);
                    cf[6]=bf2f(v3&0xffffu); cf[7]=bf2f(v3>>16);
                    uint2 o = enc8_fp8(cf);
                    if (bufi <= 2){
                        int rel = bufi - 1;
                        *(uint2*)&kvb[(size_t)(rel*NN + r)*KVSTRIDE + cw*2] = o;
                    } else {
                        int rel = bufi - 3;
                        *(uint2*)&kvb[(size_t)(rel*NN + r)*KVSTRIDE + cw*2 + 8] = o;
                    }
                }
            }
        }
    }
}

// ======================= K2: split-wave CSR attention, online softmax ==============
// kv row: 32 chunks of [kr 8B | vr 8B] -> ONE uint4 gather per edge per lane.
// round-2 proven version (depth-3 prefetch).
__global__ __launch_bounds__(256) void attn_k(const u16* __restrict__ qb,
        const u8* __restrict__ kvb,
        const int* __restrict__ row_ptr, const int* __restrict__ epk,
        u16* __restrict__ A2){
    int wv = threadIdx.x >> 6, lane = threadIdx.x & 63;
    int node = blockIdx.x*4 + wv;
    int l32 = lane & 31;
    int half = lane >> 5;
    int start = row_ptr[node], end = row_ptr[node+1];
    f32x2 qf[4];
    {
        uint4 qr = *(const uint4*)&qb[(size_t)node*256 + l32*8];
        qf[0] = (f32x2){__uint_as_float(qr.x<<16), __uint_as_float(qr.x&0xffff0000u)};
        qf[1] = (f32x2){__uint_as_float(qr.y<<16), __uint_as_float(qr.y&0xffff0000u)};
        qf[2] = (f32x2){__uint_as_float(qr.z<<16), __uint_as_float(qr.z&0xffff0000u)};
        qf[3] = (f32x2){__uint_as_float(qr.w<<16), __uint_as_float(qr.w&0xffff0000u)};
    }
    float m = -1e30f, s = 0.f;
    f32x2 acc[4];
    #pragma unroll
    for (int j=0;j<4;++j) acc[j] = (f32x2){0.f,0.f};

    int i0 = start + half;
    uint4 c0={0,0,0,0}, c1={0,0,0,0}, c2={0,0,0,0};
    if (i0     < end) c0 = *(const uint4*)&kvb[(size_t)epk[i0  ]*KVSTRIDE + l32*16];
    if (i0 + 2 < end) c1 = *(const uint4*)&kvb[(size_t)epk[i0+2]*KVSTRIDE + l32*16];
    if (i0 + 4 < end) c2 = *(const uint4*)&kvb[(size_t)epk[i0+4]*KVSTRIDE + l32*16];
    int pk = (i0 + 6 < end) ? epk[i0+6] : 0;

    for (int i = i0; i < end; i += 2){
        uint4 cc = c0; c0 = c1; c1 = c2;
        if (i + 6 < end)                       // refill depth-3 slot
            c2 = *(const uint4*)&kvb[(size_t)pk*KVSTRIDE + l32*16];
        if (i + 8 < end) pk = epk[i+8];        // index 4 deep
        f32x2 kf0 = __builtin_amdgcn_cvt_pk_f32_fp8(cc.x, false);
        f32x2 kf1 = __builtin_amdgcn_cvt_pk_f32_fp8(cc.x, true);
        f32x2 kf2 = __builtin_amdgcn_cvt_pk_f32_fp8(cc.y, false);
        f32x2 kf3 = __builtin_amdgcn_cvt_pk_f32_fp8(cc.y, true);
        f32x2 p2 = qf[0]*kf0 + qf[1]*kf1 + qf[2]*kf2 + qf[3]*kf3;
        float p = p2.x + p2.y;
        p += __shfl_xor(p, 1);
        p += __shfl_xor(p, 2);                 // logit (prel/sqrt folded into kr)
        float mo = m;
        m = fmaxf(m, p);
        float sc = __expf(mo - m);
        float pe = __expf(p - m);
        s = s*sc + pe;
        f32x2 vf0 = __builtin_amdgcn_cvt_pk_f32_fp8(cc.z, false);
        f32x2 vf1 = __builtin_amdgcn_cvt_pk_f32_fp8(cc.z, true);
        f32x2 vf2 = __builtin_amdgcn_cvt_pk_f32_fp8(cc.w, false);
        f32x2 vf3 = __builtin_amdgcn_cvt_pk_f32_fp8(cc.w, true);
        f32x2 sc2 = (f32x2){sc,sc}, pe2 = (f32x2){pe,pe};
        acc[0] = acc[0]*sc2 + pe2*vf0;
        acc[1] = acc[1]*sc2 + pe2*vf1;
        acc[2] = acc[2]*sc2 + pe2*vf2;
        acc[3] = acc[3]*sc2 + pe2*vf3;
    }
    // merge the two halves' online-softmax states (m=-1e30: no inf-inf NaN)
    float mO = __shfl_xor(m, 32);
    float mA = fmaxf(m, mO);
    float eS = __expf(m - mA);
    float sh = s * eS;
    float sA = sh + __shfl_xor(sh, 32);
    float rs = 1.f / fmaxf(sA, 1e-16f);
    float oA[8];
    #pragma unroll
    for (int j=0;j<4;++j){
        f32x2 a = acc[j] * (f32x2){eS,eS};
        oA[2*j]   = a.x + __shfl_xor(a.x, 32);
        oA[2*j+1] = a.y + __shfl_xor(a.y, 32);
    }
    if (half == 0){
        u16 o[8];
        #pragma unroll
        for (int j=0;j<8;++j) o[j] = f2bf(gelu_exact(oA[j]*rs));
        uint4 ov;
        ov.x = (unsigned)o[0] | ((unsigned)o[1]<<16);
        ov.y = (unsigned)o[2] | ((unsigned)o[3]<<16);
        ov.z = (unsigned)o[4] | ((unsigned)o[5]<<16);
        ov.w = (unsigned)o[6] | ((unsigned)o[7]<<16);
        int c0b = l32*8;
        *(uint4*)&A2[(size_t)(c0b>>5)*APAN + (size_t)node*32 + (c0b&31)] = ov;
    }
}

// ======================= K3a: out GEMM + skip + relu + LN (layers 0-2) ===========
// round-2 structure (32-row tiles, BK=64) + conflict-free fragment swizzle.
__global__ __launch_bounds__(256) void gemmOln_k(const u16* __restrict__ A,
        const u16* __restrict__ Wt, const float* __restrict__ bias,
        const float* __restrict__ h_in, const float* __restrict__ skip_l,
        const float* __restrict__ g, const float* __restrict__ b,
        float* __restrict__ h_out, u16* __restrict__ hbf){
    __shared__ __align__(16) char smem[36864];   // As 4KB + Bs 32KB; LN partials alias
    u16* As = (u16*)smem;                        // 2 panels x 32 rows x 32 k = 2048 u16
    u16* Bs = (u16*)(smem + 4096);               // 2 panels x 256 cols x 32 k = 16384 u16
    float* part_s = (float*)smem;                // [32][66]
    float* part_q = part_s + 32*66;              // [32][66]
    float* mu_s   = part_q + 32*66;              // [32]
    float* rstd_s = mu_s + 32;                   // [32]
    int tid = threadIdx.x;
    int w = tid >> 6, lane = tid & 63;
    int row0 = blockIdx.x * 32;
    f32x4 acc[2][4];
    #pragma unroll
    for (int i=0;i<2;++i)
        #pragma unroll
        for (int j=0;j<4;++j) acc[i][j] = (f32x4){0.f,0.f,0.f,0.f};

    int lm = lane & 15, quad = lane >> 4;
    int kq0 = SWZ(quad, lm);
    int aoff = lm*32 + kq0*8;
    int boff = (w*64 + lm)*32 + kq0*8;

    for (int kk2 = 0; kk2 < 4; ++kk2){
        {
            int s = tid;                       // 256 slots = 2 halves x 32 rows x 4
            int hf = s >> 7;
            int s7 = s & 127;
            int row = s7 >> 2, q0 = s7 & 3;
            int kq = SWZ(q0, row);
            gload_lds16(&A[(size_t)(kk2*2+hf)*APAN + (size_t)(row0+row)*32 + kq*8],
                        &As[(size_t)(w*64)*8]);
        }
        #pragma unroll
        for (int it = 0; it < 8; ++it){        // 2048 slots = 2 halves x 256 n-rows x 4
            int s = it*256 + tid;
            int hf = s >> 10;
            int s10 = s & 1023;
            int row = s10 >> 2, q0 = s10 & 3;
            int kq = SWZ(q0, row);
            gload_lds16(&Wt[(size_t)(kk2*2+hf)*OPAN + (size_t)row*32 + kq*8],
                        &Bs[(size_t)(it*256 + w*64)*8]);
        }
        __syncthreads();
        #pragma unroll
        for (int hf = 0; hf < 2; ++hf){
            bf16x8 af[2], bfr[4];
            #pragma unroll
            for (int mi=0; mi<2; ++mi) af[mi]  = *(bf16x8*)&As[hf*1024 + aoff + mi*512];
            #pragma unroll
            for (int ni=0; ni<4; ++ni) bfr[ni] = *(bf16x8*)&Bs[hf*8192 + boff + ni*512];
            #pragma unroll
            for (int mi=0; mi<2; ++mi)
                #pragma unroll
                for (int ni=0; ni<4; ++ni)
                    acc[mi][ni] = __builtin_amdgcn_mfma_f32_16x16x32_bf16(af[mi], bfr[ni], acc[mi][ni], 0,0,0);
        }
        __syncthreads();    // also fences As/Bs before LN-partial aliasing
    }

    float sskip = 1.f/(1.f+__expf(-skip_l[0]));
    float osk = 1.f - sskip;
    float bv[4], gv[4], bbv[4];
    #pragma unroll
    for (int ni=0; ni<4; ++ni){
        int colg = w*64 + ni*16 + lm;
        bv[ni]  = bias[colg];
        gv[ni]  = g[colg];
        bbv[ni] = b[colg];
    }
    #pragma unroll
    for (int mi=0; mi<2; ++mi){
        #pragma unroll
        for (int t=0; t<4; ++t){
            int lr = mi*16 + quad*4 + t;       // 0..31
            int r = row0 + lr;                 // always < NN (625*32 = 20000)
            float ps = 0.f, pq = 0.f;
            #pragma unroll
            for (int ni=0; ni<4; ++ni){
                int colg = w*64 + ni*16 + lm;
                float hv = h_in[(size_t)r*256 + colg];
                float val = sskip*(acc[mi][ni][t] + bv[ni]) + osk*hv;
                val = fmaxf(val, 0.f);
                acc[mi][ni][t] = val;
                ps += val; pq += val*val;
            }
            part_s[lr*66 + w*16 + lm] = ps;
            part_q[lr*66 + w*16 + lm] = pq;
        }
    }
    __syncthreads();
    if (tid < 32){
        float S = 0.f, Q = 0.f;
        #pragma unroll 8
        for (int t2=0; t2<64; ++t2){
            S += part_s[tid*66 + t2];
            Q += part_q[tid*66 + t2];
        }
        float mu = S * (1.f/256.f);
        float var = Q * (1.f/256.f) - mu*mu;
        mu_s[tid] = mu;
        rstd_s[tid] = rsqrtf(var + 1e-5f);
    }
    __syncthreads();
    #pragma unroll
    for (int mi=0; mi<2; ++mi){
        #pragma unroll
        for (int t=0; t<4; ++t){
            int lr = mi*16 + quad*4 + t;
            int r = row0 + lr;
            float mu = mu_s[lr], rstd = rstd_s[lr];
            #pragma unroll
            for (int ni=0; ni<4; ++ni){
                int colg = w*64 + ni*16 + lm;
                float o = (acc[mi][ni][t] - mu)*rstd*gv[ni] + bbv[ni];
                h_out[(size_t)r*256 + colg] = o;
                hbf[(size_t)(colg>>5)*APAN + (size_t)r*32 + (colg&31)] = f2bf(o);
            }
        }
    }
}

// ======================= K3b: out GEMM + skip blend (final layer) =======================
// 64x128 tiles -> grid (313,2); conflict-free fragment swizzle.
__global__ __launch_bounds__(256) void gemmO_k(const u16* __restrict__ A,
        const u16* __restrict__ Wt, const float* __restrict__ bias,
        const float* __restrict__ h_in, const float* __restrict__ skip_l,
        float* __restrict__ outp){
    __shared__ u16 As[2048];       // 64 rows x 32 k
    __shared__ u16 Bs[4096];       // 128 cols x 32 k
    int tid = threadIdx.x;
    int w = tid >> 6, lane = tid & 63;
    int row0 = blockIdx.x * 64;
    int col0 = blockIdx.y * 128;
    int wm = w & 1, wn = w >> 1;
    f32x4 acc[2][4];
    #pragma unroll
    for (int i=0;i<2;++i)
        #pragma unroll
        for (int j=0;j<4;++j) acc[i][j] = (f32x4){0.f,0.f,0.f,0.f};

    int lm = lane & 15, quad = lane >> 4;
    int kq0 = SWZ(quad, lm);
    int aoff = (wm*32 + lm)*32 + kq0*8;
    int boff = (wn*64 + lm)*32 + kq0*8;

    for (int kk = 0; kk < 8; ++kk){
        {
            int s = tid;                       // 256 slots = 64 rows x 4
            int row = s >> 2, q0 = s & 3;
            int kq = SWZ(q0, row);
            gload_lds16(&A[(size_t)kk*APAN + (size_t)(row0+row)*32 + kq*8],
                        &As[(size_t)(w*64)*8]);
        }
        #pragma unroll
        for (int it = 0; it < 2; ++it){        // 512 slots = 128 n-rows x 4
            int s = it*256 + tid;
            int row = s >> 2, q0 = s & 3;
            int kq = SWZ(q0, row);
            gload_lds16(&Wt[(size_t)kk*OPAN + (size_t)(col0+row)*32 + kq*8],
                        &Bs[(size_t)(it*256 + w*64)*8]);
        }
        __syncthreads();
        bf16x8 af[2], bfr[4];
        #pragma unroll
        for (int mi=0; mi<2; ++mi) af[mi]  = *(bf16x8*)&As[aoff + mi*512];
        #pragma unroll
        for (int ni=0; ni<4; ++ni) bfr[ni] = *(bf16x8*)&Bs[boff + ni*512];
        #pragma unroll
        for (int mi=0; mi<2; ++mi)
            #pragma unroll
            for (int ni=0; ni<4; ++ni)
                acc[mi][ni] = __builtin_amdgcn_mfma_f32_16x16x32_bf16(af[mi], bfr[ni], acc[mi][ni], 0,0,0);
        __syncthreads();
    }
    float s = 1.f/(1.f+expf(-skip_l[0]));
    float os = 1.f - s;
    #pragma unroll
    for (int ni=0; ni<4; ++ni){
        int colg = col0 + wn*64 + ni*16 + lm;
        float bv = bias[colg];
        #pragma unroll
        for (int mi=0; mi<2; ++mi){
            #pragma unroll
            for (int t=0; t<4; ++t){
                int r = row0 + wm*32 + mi*16 + quad*4 + t;
                if (r < NN)
                    outp[(size_t)r*256 + colg] =
                        s*(acc[mi][ni][t] + bv) + os*h_in[(size_t)r*256 + colg];
            }
        }
    }
}

// ======================= host =======================
extern "C" void kernel_launch(void* const* d_in, const int* in_sizes, int n_in,
                              void* d_out, int out_size, void* d_ws, size_t ws_size,
                              hipStream_t stream){
    (void)in_sizes; (void)n_in; (void)out_size; (void)ws_size;
    const float* x     = (const float*)d_in[0];
    const int*   ei0   = (const int*)d_in[1];
    const int*   ei1   = (const int*)d_in[2];
    const float* kqv_w = (const float*)d_in[3];
    const float* kqv_b = (const float*)d_in[4];
    const float* out_w = (const float*)d_in[5];
    const float* out_b = (const float*)d_in[6];
    const float* skip  = (const float*)d_in[7];
    const float* krel  = (const float*)d_in[8];
    const float* vrel  = (const float*)d_in[9];
    const float* prel  = (const float*)d_in[10];
    const float* ln_g  = (const float*)d_in[11];
    const float* ln_b  = (const float*)d_in[12];
    float* outp = (float*)d_out;

    char* wp = (char*)d_ws;
    auto alloc = [&](size_t bytes)->void*{
        void* p = wp; wp += (bytes + 255) & ~(size_t)255; return p;
    };
    float* hA    = (float*)alloc((size_t)NN*CC*4);
    float* hB    = (float*)alloc((size_t)NN*CC*4);
    u16*   xbf   = (u16*)alloc((size_t)NPAD*CC*2);   // k-panel layout
    u16*   hbf   = (u16*)alloc((size_t)NPAD*CC*2);   // k-panel layout
    u16*   A2    = (u16*)alloc((size_t)NPAD*CC*2);   // k-panel layout
    u16*   qb    = (u16*)alloc((size_t)NN*CC*2);
    u8*    kvb   = (u8*)alloc((size_t)2*NN*KVSTRIDE);   // [rel*NN+node][32 x (kr8|vr8)]
    u16*   Wt5   = (u16*)alloc((size_t)4*1280*256*2);   // k-panel layout
    u16*   Wto   = (u16*)alloc((size_t)4*256*256*2);    // k-panel layout
    float* bias5 = (float*)alloc((size_t)4*1280*4);
    float* sc5   = (float*)alloc((size_t)4*1280*4);
    int* cnt     = (int*)alloc((size_t)NN*4);
    int* cursor  = (int*)alloc((size_t)NN*4);
    int* incl    = (int*)alloc((size_t)NN*4);
    int* row_ptr = (int*)alloc((size_t)(NN+1)*4);
    int* bsum    = (int*)alloc(128*4);
    int* epk     = (int*)alloc((size_t)TE*4);

    // fused prep (weights + input cast + cnt/cursor zero) — one dispatch
    prep_k<<<4736,256,0,stream>>>(kqv_w, kqv_b, krel, vrel, prel, out_w, x,
                                  Wt5, xbf, Wto, bias5, sc5, cnt, cursor);

    // CSR build (cnt/cursor zeroed by prep_k on the same stream)
    hist_k<<<1250,256,0,stream>>>(ei0, ei1, cnt);
    scan_block_k<<<79,256,0,stream>>>(cnt, incl, bsum);
    finalize_rowptr_k<<<79,256,0,stream>>>(cnt, incl, bsum, row_ptr);
    scatter_k<<<1250,256,0,stream>>>(ei0, ei1, row_ptr, cursor, epk);

    const float* h_in = x;
    const u16*   Ain  = xbf;
    float* houts[4] = {hA, hB, hA, outp};
    for (int l=0; l<4; ++l){
        gemm5_k<<<1600,256,0,stream>>>(Ain, Wt5 + (size_t)l*327680,
                bias5 + l*1280, sc5 + l*1280, qb, kvb);
        attn_k<<<5000,256,0,stream>>>(qb, kvb, row_ptr, epk, A2);
        if (l < 3){
            gemmOln_k<<<625,256,0,stream>>>(A2, Wto + (size_t)l*65536,
                    out_b + l*256, h_in, skip + l, ln_g + l*256, ln_b + l*256,
                    houts[l], hbf);
        } else {
            gemmO_k<<<dim3(313,2),256,0,stream>>>(A2, Wto + (size_t)l*65536,
                    out_b + l*256, h_in, skip + l, outp);
        }
        h_in = houts[l];
        Ain = hbf;
    }
}